// Round 4
// baseline (3668.741 us; speedup 1.0000x reference)
//
#include <hip/hip_runtime.h>

#define Hh 64
#define Tt 2048
#define Bb 256
#define NL 3

__device__ __forceinline__ float fast_sigmoid(float x) {
    return 1.0f / (1.0f + __expf(-x));
}
__device__ __forceinline__ float fast_tanh(float x) {
    float e = __expf(2.0f * x);
    return 1.0f - 2.0f / (e + 1.0f);
}

__device__ __forceinline__ float fma4(float acc, const float4& a, const float4& b) {
    acc = fmaf(a.x, b.x, acc);
    acc = fmaf(a.y, b.y, acc);
    acc = fmaf(a.z, b.z, acc);
    acc = fmaf(a.w, b.w, acc);
    return acc;
}

// One block per batch element, 6 waves = 2 waves per GRU layer.
// Layers are software-pipelined with skew 1: at phase p, layer l does t = p - l.
// Per layer, the 6 dot products split by ROWS across the wave pair (no
// partial-sum reduction):
//   s=0: {Wih_r . x, Whh_r . h, Whh_n . h} -> r = sig(.), u = r * (Whh_n.h + bhn)
//   s=1: {Wih_z . x, Whh_z . h, Wih_n . x} -> z = sig(.), then n = tanh(axn + u),
//        h_new = (1-z)*n + z*h
// Per-lane weights: 3 rows x 64 = 192 VGPR -> fits the 256-reg/2-wave cap, no spill.
// Activations cross waves via LDS broadcast (uniform-address float4 reads).
__global__ __launch_bounds__(384, 1)
void gru_pipe(const float* __restrict__ in, float* __restrict__ out,
              const float* __restrict__ Wih, const float* __restrict__ Whh,
              const float* __restrict__ bih, const float* __restrict__ bhh)
{
    const int b   = blockIdx.x;
    const int tid = threadIdx.x;
    const int w   = tid >> 6;    // wave 0..5
    const int l   = w >> 1;      // layer 0..2
    const int s   = w & 1;       // role within layer
    const int i   = tid & 63;    // hidden unit

    const float* WihL = Wih + (long)l * 192 * 64;
    const float* WhhL = Whh + (long)l * 192 * 64;

    // wa: x-operand row, wb: h-operand row, wc: third row (h-side for s=0, x-side for s=1)
    const float* pa = s ? (WihL + (long)(64 + i) * 64) : (WihL + (long)i * 64);
    const float* pb = s ? (WhhL + (long)(64 + i) * 64) : (WhhL + (long)i * 64);
    const float* pc = s ? (WihL + (long)(128 + i) * 64) : (WhhL + (long)(128 + i) * 64);

    float4 wa[16], wb[16], wc[16];
#pragma unroll
    for (int k = 0; k < 16; ++k) {
        wa[k] = ((const float4*)pa)[k];
        wb[k] = ((const float4*)pb)[k];
        wc[k] = ((const float4*)pc)[k];
    }
    // bias: accA seeds the sigmoid arg (both its biases), accC seeds the third dot
    const float bA = s ? (bih[l*192 + 64 + i] + bhh[l*192 + 64 + i])
                       : (bih[l*192 + i]      + bhh[l*192 + i]);
    const float bC = s ? bih[l*192 + 128 + i] : bhh[l*192 + 128 + i];

    __shared__ float hbuf[NL][2][Hh];   // per-layer h, double-buffered by parity
    __shared__ float xbuf[2][Hh];       // layer-0 input, double-buffered
    __shared__ float ubuf[NL][Hh];      // r * (Whh_n . h + bhn), s=0 -> s=1

    const long ib = (long)b * Hh * Tt;  // [B,H,T]

    // init
    hbuf[l][0][i] = 0.0f;               // (waves 0/1, 2/3, 4/5 write same values: benign)
    hbuf[l][1][i] = 0.0f;
    float hprev = 0.0f;                 // live in s=1 lanes
    float xcur = 0.0f, xnext = 0.0f;    // live in wave 4 (l=2, s=0): x prefetch duty
    if (w == 4) {
        xbuf[0][i] = in[ib + (long)i * Tt + 0];
        xcur       = in[ib + (long)i * Tt + 1];
    }
    __syncthreads();

    for (int p = 0; p < Tt + NL - 1; ++p) {
        const int rd = p & 1;
        const int wr = rd ^ 1;
        const int t  = p - l;
        const bool act = (t >= 0) && (t < Tt);

        // x prefetch issue at phase top: latency hides under the dot phase
        if (w == 4 && p + 2 < Tt) xnext = in[ib + (long)i * Tt + (p + 2)];

        float accA = bA, accB = 0.0f, accC = bC;
        if (act) {
            const float4* xs4 = (const float4*)((l == 0) ? xbuf[rd] : hbuf[l - 1][rd]);
            const float4* hs4 = (const float4*)hbuf[l][rd];
            if (s == 0) {
#pragma unroll
                for (int k = 0; k < 16; ++k) {
                    const float4 xv = xs4[k];   // uniform addr -> broadcast
                    const float4 hv = hs4[k];
                    accA = fma4(accA, wa[k], xv);
                    accB = fma4(accB, wb[k], hv);
                    accC = fma4(accC, wc[k], hv);
                }
            } else {
#pragma unroll
                for (int k = 0; k < 16; ++k) {
                    const float4 xv = xs4[k];
                    const float4 hv = hs4[k];
                    accA = fma4(accA, wa[k], xv);
                    accB = fma4(accB, wb[k], hv);
                    accC = fma4(accC, wc[k], xv);
                }
            }
            const float g = fast_sigmoid(accA + accB);   // r (s=0) or z (s=1)
            if (s == 0) {
                ubuf[l][i] = g * accC;                   // u = r * (Whh_n.h + bhn)
            }
            accA = g;                                    // carry gate value across B1
        }
        __syncthreads();   // B1: u visible

        if (act && s == 1) {
            const float n = fast_tanh(accC + ubuf[l][i]);        // accC = Wih_n.x + bxn
            const float hnew = fmaf(accA, hprev - n, n);         // (1-z)*n + z*h
            hprev = hnew;
            hbuf[l][wr][i] = hnew;
            if (l == NL - 1) out[ib + (long)i * Tt + t] = hnew;
        }
        if (w == 4) {
            if (p + 1 < Tt) xbuf[wr][i] = xcur;
            xcur = xnext;
        }
        __syncthreads();   // B2: h/x published for next phase
    }
}

extern "C" void kernel_launch(void* const* d_in, const int* in_sizes, int n_in,
                              void* d_out, int out_size, void* d_ws, size_t ws_size,
                              hipStream_t stream) {
    const float* x   = (const float*)d_in[0];   // [B, H, T]
    const float* Wih = (const float*)d_in[1];   // [3, 192, 64]
    const float* Whh = (const float*)d_in[2];   // [3, 192, 64]
    const float* bih = (const float*)d_in[3];   // [3, 192]
    const float* bhh = (const float*)d_in[4];   // [3, 192]
    float* out = (float*)d_out;                 // [B, H, T]

    gru_pipe<<<Bb, 384, 0, stream>>>(x, out, Wih, Whh, bih, bhh);
}